// Round 12
// baseline (116.437 us; speedup 1.0000x reference)
//
#include <hip/hip_runtime.h>
#include <hip/hip_bf16.h>

#define IW    4096
#define OW    4096
#define PC    64
#define BATCH 1024
#define BQ    256          // batch-quarter: 2MB contiguous block per quarter

__device__ __forceinline__ float sigmoidf_(float x) {
    return 1.0f / (1.0f + __expf(-x));
}

__device__ __forceinline__ unsigned short f2bfbits(float f) {
    union { __hip_bfloat16 h; unsigned short u; } cv;
    cv.h = __float2bfloat16(f);   // RNE
    return cv.u;
}

// K1: x [BATCH][IW] f32 -> xT quarter-major: xT[q][IW][BQ] bf16.
__global__ __launch_bounds__(256) void k_transpose_cast(
        const float* __restrict__ x, unsigned short* __restrict__ xT) {
    __shared__ float tile[64][65];          // [c_local][b_local], +1 pad
    const int c0   = blockIdx.x * 64;       // input-width tile
    const int b0   = blockIdx.y * 64;       // batch tile
    const int q    = b0 >> 8;               // quarter
    const int brem = b0 & (BQ - 1);         // batch offset within quarter
    const int t  = threadIdx.x;
    const int r  = t >> 4;                  // 0..15
    const int s  = t & 15;                  // 0..15
    #pragma unroll
    for (int it = 0; it < 4; ++it) {
        const int row = r + 16 * it;        // batch row in tile
        const float4 v = *reinterpret_cast<const float4*>(
            x + (size_t)(b0 + row) * IW + c0 + s * 4);
        tile[s * 4 + 0][row] = v.x;
        tile[s * 4 + 1][row] = v.y;
        tile[s * 4 + 2][row] = v.z;
        tile[s * 4 + 3][row] = v.w;
    }
    __syncthreads();
    unsigned short* dst = xT + (size_t)q * IW * BQ;
    #pragma unroll
    for (int it = 0; it < 4; ++it) {
        const int c = r + 16 * it;          // c_local
        ushort4 o;
        o.x = f2bfbits(tile[c][s * 4 + 0]);
        o.y = f2bfbits(tile[c][s * 4 + 1]);
        o.z = f2bfbits(tile[c][s * 4 + 2]);
        o.w = f2bfbits(tile[c][s * 4 + 3]);
        *reinterpret_cast<ushort4*>(dst + (size_t)(c0 + c) * BQ + brem + s * 4) = o;
    }
}

// K2 (fused, 4-deep): 1024 blocks, XCD-pinned quarters; block = 16 outputs x
// one 256-batch quarter. Gather: split-wave dwordx4 (lanes 0-31 even-p rows,
// 32-63 odd-p), NORMAL loads, SINGLE pass with 4-output interleave ->
// 4 independent load streams (~16 loads in flight/wave) to test whether the
// ~12.8 TB/s random-L2 plateau is latency- or bandwidth-bound.
// Epilogue: stage 16x256 f32 tile in LDS, write out[b][o0:o15] directly.
__global__ __launch_bounds__(256) void k_gather_fused(
        const unsigned short* __restrict__ xT,
        const int* __restrict__ sel,
        const float* __restrict__ wts,
        const float* __restrict__ biases,
        float* __restrict__ out) {
    __shared__ int   s_off[16][PC];
    __shared__ float s_wa[16][PC];
    __shared__ float otile[16][BQ + 4];               // 16 outputs x 256 batches, padded
    const int bid = blockIdx.x;
    const int xcd = bid & 7;
    const int q   = xcd & 3;                          // this XCD's quarter
    const int g   = ((bid >> 3) << 1) + (xcd >> 2);   // 0..255
    const int t   = threadIdx.x;
    // Stage params for the block's 16 outputs: 1024 entries, 4 per thread.
    #pragma unroll
    for (int r = 0; r < 4; ++r) {
        const int e  = t + 256 * r;
        const int oi = e >> 6;
        const int p  = e & 63;
        const int gi = (g * 16 + oi) * PC + p;
        s_off[oi][p] = sel[gi] * (BQ * 2);            // row byte offset in quarter
        s_wa[oi][p]  = sigmoidf_(wts[gi]);
    }
    __syncthreads();
    const int wv   = t >> 6;
    const int lane = t & 63;
    const int half = lane >> 5;                       // 0: even p, 1: odd p
    const int l31  = lane & 31;
    const int bq   = q * BQ;
    // per-lane base: quarter base + 16B column slot within each row
    const char* baseq = (const char*)xT + (size_t)q * (IW * BQ * 2) + (size_t)l31 * 16;
    const int o0 = wv * 4;                            // this wave's 4 outputs
    float a[4][8] = {};
    #pragma unroll 2
    for (int p2 = 0; p2 < PC / 2; ++p2) {
        #pragma unroll
        for (int j = 0; j < 4; ++j) {
            const int2   offs = *reinterpret_cast<const int2*>(&s_off[o0 + j][2 * p2]);
            const float2 wsp  = *reinterpret_cast<const float2*>(&s_wa[o0 + j][2 * p2]);
            const int   off = half ? offs.y : offs.x;
            const float wj  = half ? wsp.y  : wsp.x;
            const uint4 r = *reinterpret_cast<const uint4*>(baseq + off);
            a[j][0] = fmaf(wj, __uint_as_float(r.x << 16),         a[j][0]);
            a[j][1] = fmaf(wj, __uint_as_float(r.x & 0xffff0000u), a[j][1]);
            a[j][2] = fmaf(wj, __uint_as_float(r.y << 16),         a[j][2]);
            a[j][3] = fmaf(wj, __uint_as_float(r.y & 0xffff0000u), a[j][3]);
            a[j][4] = fmaf(wj, __uint_as_float(r.z << 16),         a[j][4]);
            a[j][5] = fmaf(wj, __uint_as_float(r.z & 0xffff0000u), a[j][5]);
            a[j][6] = fmaf(wj, __uint_as_float(r.w << 16),         a[j][6]);
            a[j][7] = fmaf(wj, __uint_as_float(r.w & 0xffff0000u), a[j][7]);
        }
    }
    // recombine even-p (lanes 0-31) with odd-p (lanes 32-63) partials
    #pragma unroll
    for (int j = 0; j < 4; ++j)
        #pragma unroll
        for (int k = 0; k < 8; ++k)
            a[j][k] += __shfl_xor(a[j][k], 32);
    // lane (half,l31) owns batches l31*8 + half*4 .. +3
    const int k0 = half * 4;
    const int bl = l31 * 8 + k0;
    #pragma unroll
    for (int j = 0; j < 4; ++j) {
        const float bo = biases[g * 16 + o0 + j];
        float4 f;
        f.x = sigmoidf_(a[j][k0 + 0] - bo);
        f.y = sigmoidf_(a[j][k0 + 1] - bo);
        f.z = sigmoidf_(a[j][k0 + 2] - bo);
        f.w = sigmoidf_(a[j][k0 + 3] - bo);
        *reinterpret_cast<float4*>(&otile[o0 + j][bl]) = f;
    }
    __syncthreads();
    // write-out: thread t = batch b_local; out[bq+t][g*16 .. +15] = 64B
    {
        const int oG = g * 16;
        float4 v0, v1, v2, v3;
        v0.x = otile[ 0][t]; v0.y = otile[ 1][t]; v0.z = otile[ 2][t]; v0.w = otile[ 3][t];
        v1.x = otile[ 4][t]; v1.y = otile[ 5][t]; v1.z = otile[ 6][t]; v1.w = otile[ 7][t];
        v2.x = otile[ 8][t]; v2.y = otile[ 9][t]; v2.z = otile[10][t]; v2.w = otile[11][t];
        v3.x = otile[12][t]; v3.y = otile[13][t]; v3.z = otile[14][t]; v3.w = otile[15][t];
        float* dst = out + (size_t)(bq + t) * OW + oG;
        *reinterpret_cast<float4*>(dst +  0) = v0;
        *reinterpret_cast<float4*>(dst +  4) = v1;
        *reinterpret_cast<float4*>(dst +  8) = v2;
        *reinterpret_cast<float4*>(dst + 12) = v3;
    }
}

// Fallback (correctness-only) if ws is too small for staging.
__global__ __launch_bounds__(256) void k_naive(
        const float* __restrict__ x, const int* __restrict__ sel,
        const float* __restrict__ w, const float* __restrict__ biases,
        float* __restrict__ out) {
    __shared__ int   s_idx[PC];
    __shared__ float s_wa[PC];
    const int o = blockIdx.x;
    const int t = threadIdx.x;
    if (t < PC) {
        s_idx[t] = sel[o * PC + t];
        s_wa[t]  = sigmoidf_(w[o * PC + t]);
    }
    __syncthreads();
    const int b4 = t * 4;
    float a[4] = {0.f, 0.f, 0.f, 0.f};
    for (int p = 0; p < PC; ++p) {
        const int   idx = s_idx[p];
        const float wa  = s_wa[p];
        #pragma unroll
        for (int k = 0; k < 4; ++k)
            a[k] = fmaf(wa, x[(size_t)(b4 + k) * IW + idx], a[k]);
    }
    const float bo = biases[o];
    #pragma unroll
    for (int k = 0; k < 4; ++k)
        out[(size_t)(b4 + k) * OW + o] = sigmoidf_(a[k] - bo);
}

extern "C" void kernel_launch(void* const* d_in, const int* in_sizes, int n_in,
                              void* d_out, int out_size, void* d_ws, size_t ws_size,
                              hipStream_t stream) {
    const float* x      = (const float*)d_in[0];
    const int*   sel    = (const int*)d_in[1];
    const float* w      = (const float*)d_in[2];
    const float* biases = (const float*)d_in[3];
    float*       out    = (float*)d_out;

    const size_t xT_bytes = (size_t)IW * BATCH * 2;   // 8 MB

    if (ws_size >= xT_bytes) {
        unsigned short* xT = (unsigned short*)d_ws;
        k_transpose_cast<<<dim3(IW / 64, BATCH / 64), 256, 0, stream>>>(x, xT);
        k_gather_fused<<<dim3(1024), 256, 0, stream>>>(xT, sel, w, biases, out);
    } else {
        k_naive<<<OW, 256, 0, stream>>>(x, sel, w, biases, out);
    }
}

// Round 14
// 104.490 us; speedup vs baseline: 1.1143x; 1.1143x over previous
//
#include <hip/hip_runtime.h>
#include <hip/hip_bf16.h>

#define IW    4096
#define OW    4096
#define PC    64
#define BATCH 1024
#define SB    8            // batches per slice; slice = 4096 rows x 8 x bf16 = 64 KB LDS
#define NSLICE (BATCH / SB)   // 128
#define OQ    4               // output quarters -> grid 512 = 2 blocks/CU

__device__ __forceinline__ float sigmoidf_(float x) {
    return 1.0f / (1.0f + __expf(-x));
}

__device__ __forceinline__ unsigned short f2bfbits(float f) {
    union { __hip_bfloat16 h; unsigned short u; } cv;
    cv.h = __float2bfloat16(f);   // RNE
    return cv.u;
}

// K1: x [BATCH][IW] f32 -> xS slice-major: xS[slice][IW][SB] bf16.
__global__ __launch_bounds__(256) void k_transpose_cast(
        const float* __restrict__ x, unsigned short* __restrict__ xS) {
    __shared__ float tile[64][65];          // [c_local][b_local], +1 pad
    const int c0 = blockIdx.x * 64;         // input-width tile
    const int b0 = blockIdx.y * 64;         // batch tile
    const int t  = threadIdx.x;
    const int r  = t >> 4;                  // 0..15
    const int s  = t & 15;                  // 0..15
    #pragma unroll
    for (int it = 0; it < 4; ++it) {
        const int row = r + 16 * it;        // batch row in tile
        const float4 v = *reinterpret_cast<const float4*>(
            x + (size_t)(b0 + row) * IW + c0 + s * 4);
        tile[s * 4 + 0][row] = v.x;
        tile[s * 4 + 1][row] = v.y;
        tile[s * 4 + 2][row] = v.z;
        tile[s * 4 + 3][row] = v.w;
    }
    __syncthreads();
    const int b4    = b0 + s * 4;           // first batch of this thread's quad
    const int slice = b4 >> 3;
    const int pos   = b4 & 7;               // 0 or 4
    unsigned short* dst = xS + (size_t)slice * IW * SB + pos;
    #pragma unroll
    for (int it = 0; it < 4; ++it) {
        const int c = r + 16 * it;          // c_local
        ushort4 o;
        o.x = f2bfbits(tile[c][s * 4 + 0]);
        o.y = f2bfbits(tile[c][s * 4 + 1]);
        o.z = f2bfbits(tile[c][s * 4 + 2]);
        o.w = f2bfbits(tile[c][s * 4 + 3]);
        *reinterpret_cast<ushort4*>(dst + (size_t)(c0 + c) * SB) = o;
    }
}

// P0: p-major param table: pairT[p*OW + o] = {sel[o][p]*16 (LDS byte offset),
// f32 bits of sigmoid(w[o][p])}. Read in K2 as coalesced 512B wave-loads.
__global__ __launch_bounds__(256) void k_prep_params(
        const int* __restrict__ sel, const float* __restrict__ wts,
        int2* __restrict__ pairT) {
    const int tid = blockIdx.x * 256 + threadIdx.x;   // 0 .. OW*PC-1
    const int o = tid & (OW - 1);
    const int p = tid >> 12;
    const int gi = o * PC + p;
    int2 e;
    e.x = sel[gi] * (SB * 2);               // byte offset of row in 64KB slice
    e.y = __float_as_int(sigmoidf_(wts[gi]));
    pairT[(size_t)p * OW + o] = e;
}

// K2 (LDS gather v2): grid 512 = NSLICE(128) x OQ(4); 512 threads, 64KB LDS
// -> 2 blocks/CU, 16 waves/CU. Block stages one 8-batch slice (all 4096
// rows), then each lane owns 2 outputs (o0, o0+64) across all 8 batches:
// row-per-lane ds_read_b128 gather (64 random rows per wave-instr), params
// prefetched 1 iteration ahead via coalesced 512B global loads (no
// dependent-chain stall), accumulate 16 f32, write f32 out directly
// (coalesced 256B row-chunks). No shuffles, no output transpose.
__global__ __launch_bounds__(512, 4) void k_gather_lds2(
        const unsigned short* __restrict__ xS,
        const int2* __restrict__ pairT,
        const float* __restrict__ biases,
        float* __restrict__ out) {
    __shared__ unsigned short lds[IW * SB];           // 64 KB
    const int bid   = blockIdx.x;
    const int slice = bid >> 2;                       // 0..127
    const int oq    = bid & 3;                        // output quarter
    const int t     = threadIdx.x;
    // stage slice: 8 rounds x 512 threads x 16B = 64 KB, coalesced
    {
        const uint4* src = reinterpret_cast<const uint4*>(xS + (size_t)slice * IW * SB);
        uint4* dst = reinterpret_cast<uint4*>(lds);
        #pragma unroll
        for (int it = 0; it < 8; ++it)
            dst[t + 512 * it] = src[t + 512 * it];
    }
    __syncthreads();
    const int wv   = t >> 6;                          // 0..7
    const int lane = t & 63;
    const int o0   = oq * 1024 + wv * 128 + lane;
    const int o1   = o0 + 64;
    float a0[8] = {};
    float a1[8] = {};
    int2 c0 = pairT[o0];                              // p = 0
    int2 c1 = pairT[o1];
    #pragma unroll 4
    for (int p = 0; p < PC; ++p) {
        const int pn = (p + 1 < PC) ? (p + 1) : (PC - 1);
        const int2 n0 = pairT[(size_t)pn * OW + o0];  // prefetch next params
        const int2 n1 = pairT[(size_t)pn * OW + o1];
        const uint4 r0 = *reinterpret_cast<const uint4*>((const char*)lds + c0.x);
        const uint4 r1 = *reinterpret_cast<const uint4*>((const char*)lds + c1.x);
        const float w0 = __int_as_float(c0.y);
        const float w1 = __int_as_float(c1.y);
        a0[0] = fmaf(w0, __uint_as_float(r0.x << 16),         a0[0]);
        a0[1] = fmaf(w0, __uint_as_float(r0.x & 0xffff0000u), a0[1]);
        a0[2] = fmaf(w0, __uint_as_float(r0.y << 16),         a0[2]);
        a0[3] = fmaf(w0, __uint_as_float(r0.y & 0xffff0000u), a0[3]);
        a0[4] = fmaf(w0, __uint_as_float(r0.z << 16),         a0[4]);
        a0[5] = fmaf(w0, __uint_as_float(r0.z & 0xffff0000u), a0[5]);
        a0[6] = fmaf(w0, __uint_as_float(r0.w << 16),         a0[6]);
        a0[7] = fmaf(w0, __uint_as_float(r0.w & 0xffff0000u), a0[7]);
        a1[0] = fmaf(w1, __uint_as_float(r1.x << 16),         a1[0]);
        a1[1] = fmaf(w1, __uint_as_float(r1.x & 0xffff0000u), a1[1]);
        a1[2] = fmaf(w1, __uint_as_float(r1.y << 16),         a1[2]);
        a1[3] = fmaf(w1, __uint_as_float(r1.y & 0xffff0000u), a1[3]);
        a1[4] = fmaf(w1, __uint_as_float(r1.z << 16),         a1[4]);
        a1[5] = fmaf(w1, __uint_as_float(r1.z & 0xffff0000u), a1[5]);
        a1[6] = fmaf(w1, __uint_as_float(r1.w << 16),         a1[6]);
        a1[7] = fmaf(w1, __uint_as_float(r1.w & 0xffff0000u), a1[7]);
        c0 = n0;
        c1 = n1;
    }
    const float b0v = biases[o0];
    const float b1v = biases[o1];
    // word k of r.x/y/z/w: lo = batch 2j, hi = batch 2j+1 -> a[2j],a[2j+1]
    #pragma unroll
    for (int b = 0; b < 8; ++b) {
        out[(size_t)(slice * SB + b) * OW + o0] = sigmoidf_(a0[b] - b0v);
        out[(size_t)(slice * SB + b) * OW + o1] = sigmoidf_(a1[b] - b1v);
    }
}

// Fallback (correctness-only) if ws is too small for staging.
__global__ __launch_bounds__(256) void k_naive(
        const float* __restrict__ x, const int* __restrict__ sel,
        const float* __restrict__ w, const float* __restrict__ biases,
        float* __restrict__ out) {
    __shared__ int   s_idx[PC];
    __shared__ float s_wa[PC];
    const int o = blockIdx.x;
    const int t = threadIdx.x;
    if (t < PC) {
        s_idx[t] = sel[o * PC + t];
        s_wa[t]  = sigmoidf_(w[o * PC + t]);
    }
    __syncthreads();
    const int b4 = t * 4;
    float a[4] = {0.f, 0.f, 0.f, 0.f};
    for (int p = 0; p < PC; ++p) {
        const int   idx = s_idx[p];
        const float wa  = s_wa[p];
        #pragma unroll
        for (int k = 0; k < 4; ++k)
            a[k] = fmaf(wa, x[(size_t)(b4 + k) * IW + idx], a[k]);
    }
    const float bo = biases[o];
    #pragma unroll
    for (int k = 0; k < 4; ++k)
        out[(size_t)(b4 + k) * OW + o] = sigmoidf_(a[k] - bo);
}

extern "C" void kernel_launch(void* const* d_in, const int* in_sizes, int n_in,
                              void* d_out, int out_size, void* d_ws, size_t ws_size,
                              hipStream_t stream) {
    const float* x      = (const float*)d_in[0];
    const int*   sel    = (const int*)d_in[1];
    const float* w      = (const float*)d_in[2];
    const float* biases = (const float*)d_in[3];
    float*       out    = (float*)d_out;

    const size_t xS_bytes = (size_t)IW * BATCH * 2;            // 8 MB
    const size_t pt_bytes = (size_t)OW * PC * sizeof(int2);    // 2 MB

    if (ws_size >= xS_bytes + pt_bytes) {
        unsigned short* xS = (unsigned short*)d_ws;
        int2*           pT = (int2*)((char*)d_ws + xS_bytes);
        k_transpose_cast<<<dim3(IW / 64, BATCH / 64), 256, 0, stream>>>(x, xS);
        k_prep_params<<<dim3(OW * PC / 256), 256, 0, stream>>>(sel, w, pT);
        k_gather_lds2<<<dim3(NSLICE * OQ), 512, 0, stream>>>(xS, pT, biases, out);
    } else {
        k_naive<<<OW, 256, 0, stream>>>(x, sel, w, biases, out);
    }
}